// Round 1
// baseline (333.330 us; speedup 1.0000x reference)
//
#include <hip/hip_runtime.h>
#include <hip/hip_bf16.h>
#include <math.h>

#define B_ 2
#define T_ 2048
#define D_ 1024
#define H_ 16
#define HD 64

typedef __bf16 bf16;
typedef bf16 bf16x8 __attribute__((ext_vector_type(8)));
typedef float f32x4 __attribute__((ext_vector_type(4)));

// ---------------------------------------------------------------- cast x->bf16
__global__ __launch_bounds__(256) void cast_f32_bf16(const float* __restrict__ in,
                                                     bf16* __restrict__ out, int n) {
    int i = (blockIdx.x * 256 + threadIdx.x) * 4;
    if (i + 3 < n) {
        float4 v = *(const float4*)(in + i);
        bf16 o0 = (bf16)v.x, o1 = (bf16)v.y, o2 = (bf16)v.z, o3 = (bf16)v.w;
        bf16 tmp[4] = {o0, o1, o2, o3};
        *(uint2*)(out + i) = *(const uint2*)tmp;  // 8B store
    }
}

// ------------------------------------------- W[k][n] f32 -> Wt[n][k] bf16 (1024x1024)
__global__ __launch_bounds__(256) void transpose_cast(const float* __restrict__ W,
                                                      bf16* __restrict__ Wt) {
    __shared__ bf16 tile[64 * 72];  // [n_local][k_local], pitch 72 (144B, 16B-aligned)
    const int k0 = blockIdx.y * 64, n0 = blockIdx.x * 64;
    const int tid = threadIdx.x;
    for (int it = 0; it < 4; ++it) {
        int idx = it * 256 + tid;        // 1024 slots = 64 rows x 16 float4
        int r = idx >> 4;                // k row
        int c4 = (idx & 15) << 2;        // n col
        float4 v = *(const float4*)(W + (size_t)(k0 + r) * D_ + n0 + c4);
        tile[(c4 + 0) * 72 + r] = (bf16)v.x;
        tile[(c4 + 1) * 72 + r] = (bf16)v.y;
        tile[(c4 + 2) * 72 + r] = (bf16)v.z;
        tile[(c4 + 3) * 72 + r] = (bf16)v.w;
    }
    __syncthreads();
    for (int it = 0; it < 2; ++it) {
        int idx = it * 256 + tid;        // 512 slots = 64 rows x 8 groups of 8
        int r = idx >> 3;                // n row
        int c8 = (idx & 7) << 3;         // k col
        bf16x8 v = *(const bf16x8*)&tile[r * 72 + c8];
        *(bf16x8*)(Wt + (size_t)(n0 + r) * D_ + k0 + c8) = v;
    }
}

// ---------------------------------------------------------------- MFMA GEMM
// C[M,N] = A[M,K] @ Bt[N,K]^T.  BM=BN=128, BK=32, 256 thr = 4 waves, each 64x64.
// mode 0: out bf16, permuted to [B,H,T,hd] (Q/K/V via blockIdx.z)
// mode 1: out fp32, plain row-major
#define LDA 40  // padded LDS pitch (80B: rows r,r+8 alias -> 2-way, free per m136)

__global__ __launch_bounds__(256) void gemm_bf16(const bf16* __restrict__ A,
                                                 const bf16* __restrict__ Bt,
                                                 void* __restrict__ Cout,
                                                 int M, int N, int K, int mode) {
    __shared__ bf16 As[128 * LDA];
    __shared__ bf16 Bs[128 * LDA];
    const int tid = threadIdx.x;
    const int wave = tid >> 6, lane = tid & 63;
    const int quad = lane >> 4, l16 = lane & 15;
    const int wr = wave >> 1, wc = wave & 1;
    const int m0 = blockIdx.y * 128, n0 = blockIdx.x * 128;
    const int z = blockIdx.z;
    const bf16* Az = A;
    const bf16* Bz = Bt + (size_t)z * N * K;

    f32x4 acc[4][4];
    for (int mi = 0; mi < 4; ++mi)
        for (int ni = 0; ni < 4; ++ni) acc[mi][ni] = (f32x4){0.f, 0.f, 0.f, 0.f};

    for (int kb = 0; kb < K; kb += 32) {
        for (int it = 0; it < 2; ++it) {
            int idx = it * 256 + tid;     // 512 slots = 128 rows x 4 groups of 8
            int r = idx >> 2, c8 = (idx & 3) << 3;
            *(bf16x8*)&As[r * LDA + c8] = *(const bf16x8*)(Az + (size_t)(m0 + r) * K + kb + c8);
            *(bf16x8*)&Bs[r * LDA + c8] = *(const bf16x8*)(Bz + (size_t)(n0 + r) * K + kb + c8);
        }
        __syncthreads();
        bf16x8 af[4], bfr[4];
        for (int mi = 0; mi < 4; ++mi)
            af[mi] = *(const bf16x8*)&As[(wr * 64 + mi * 16 + l16) * LDA + quad * 8];
        for (int ni = 0; ni < 4; ++ni)
            bfr[ni] = *(const bf16x8*)&Bs[(wc * 64 + ni * 16 + l16) * LDA + quad * 8];
        for (int mi = 0; mi < 4; ++mi)
            for (int ni = 0; ni < 4; ++ni)
                acc[mi][ni] = __builtin_amdgcn_mfma_f32_16x16x32_bf16(af[mi], bfr[ni],
                                                                      acc[mi][ni], 0, 0, 0);
        __syncthreads();
    }

    // C/D layout: col = lane&15, row = quad*4 + reg  [m89/m91-verified]
    if (mode == 0) {
        bf16* Cb = (bf16*)Cout + (size_t)z * M * N;
        for (int mi = 0; mi < 4; ++mi)
            for (int ni = 0; ni < 4; ++ni)
                for (int r = 0; r < 4; ++r) {
                    int m = m0 + wr * 64 + mi * 16 + quad * 4 + r;
                    int n = n0 + wc * 64 + ni * 16 + l16;
                    int b = m >> 11, t = m & (T_ - 1);
                    int h = n >> 6, d = n & (HD - 1);
                    Cb[((((size_t)b * H_ + h) * T_ + t) << 6) + d] = (bf16)acc[mi][ni][r];
                }
    } else {
        float* Cf = (float*)Cout;
        for (int mi = 0; mi < 4; ++mi)
            for (int ni = 0; ni < 4; ++ni)
                for (int r = 0; r < 4; ++r) {
                    int m = m0 + wr * 64 + mi * 16 + quad * 4 + r;
                    int n = n0 + wc * 64 + ni * 16 + l16;
                    Cf[(size_t)m * N + n] = acc[mi][ni][r];
                }
    }
}

// ---------------------------------------------------------------- flash attention
// Q/K/V: [B,H,T,hd] bf16.  Out: [B,T,H,hd] bf16.
// Block = 256 thr = 4 waves; Br=64 (16 q-rows/wave), Bc=64.
#define LDT 72

__global__ __launch_bounds__(256) void attn_kernel(const bf16* __restrict__ Q,
                                                   const bf16* __restrict__ K,
                                                   const bf16* __restrict__ V,
                                                   bf16* __restrict__ O) {
    __shared__ bf16 Ks[64 * LDT];   // [key][dim]
    __shared__ bf16 Vt[64 * LDT];   // [dim][key]
    __shared__ bf16 Ps[64 * LDT];   // [q_local][key]

    const int qt = blockIdx.x;                 // q tile, 0..31
    const int bh = blockIdx.y;                 // 0..31
    const int h = bh & (H_ - 1), b = bh >> 4;
    const int tid = threadIdx.x;
    const int wave = tid >> 6, lane = tid & 63;
    const int quad = lane >> 4, l16 = lane & 15;

    const size_t base = (size_t)bh * T_ * HD;
    const bf16* Qb = Q + base;
    const bf16* Kb = K + base;
    const bf16* Vb = V + base;

    const float slope = exp2f(-0.5f * (float)(h + 1));  // get_slopes(16)

    // Q fragments in registers (A layout: m=l16, k=quad*8+j), two 32-wide k-steps
    bf16x8 qf[2];
    {
        const bf16* qrow = Qb + (size_t)(qt * 64 + wave * 16 + l16) * HD + quad * 8;
        qf[0] = *(const bf16x8*)(qrow);
        qf[1] = *(const bf16x8*)(qrow + 32);
    }

    f32x4 acc_o[4];
    float m_prev[4], l_sum[4];
    for (int df = 0; df < 4; ++df) acc_o[df] = (f32x4){0.f, 0.f, 0.f, 0.f};
    for (int r = 0; r < 4; ++r) { m_prev[r] = -INFINITY; l_sum[r] = 0.f; }

    const int qrow0 = qt * 64 + wave * 16 + quad * 4;  // + r

    for (int kt = 0; kt <= qt; ++kt) {
        __syncthreads();
        for (int it = 0; it < 2; ++it) {
            int idx = it * 256 + tid;   // 512 = 64 rows x 8 groups
            int r = idx >> 3, c8 = (idx & 7) << 3;
            // K tile [key][dim]
            *(bf16x8*)&Ks[r * LDT + c8] = *(const bf16x8*)(Kb + (size_t)(kt * 64 + r) * HD + c8);
            // V tile transposed -> [dim][key]
            bf16x8 v = *(const bf16x8*)(Vb + (size_t)(kt * 64 + r) * HD + c8);
            for (int j = 0; j < 8; ++j) Vt[(c8 + j) * LDT + r] = v[j];
        }
        __syncthreads();

        // S = Q K^T  (4 key-frags x 2 k-steps)
        f32x4 s[4];
        for (int nf = 0; nf < 4; ++nf) {
            bf16x8 kf0 = *(const bf16x8*)&Ks[(nf * 16 + l16) * LDT + quad * 8];
            bf16x8 kf1 = *(const bf16x8*)&Ks[(nf * 16 + l16) * LDT + 32 + quad * 8];
            f32x4 z = (f32x4){0.f, 0.f, 0.f, 0.f};
            z = __builtin_amdgcn_mfma_f32_16x16x32_bf16(qf[0], kf0, z, 0, 0, 0);
            z = __builtin_amdgcn_mfma_f32_16x16x32_bf16(qf[1], kf1, z, 0, 0, 0);
            s[nf] = z;
        }

        // scale + alibi + causal mask
        const bool diag = (kt == qt);
        for (int nf = 0; nf < 4; ++nf) {
            int j = kt * 64 + nf * 16 + l16;
            float ab = slope * (float)(j - (T_ - 1));
            for (int r = 0; r < 4; ++r) {
                float v = s[nf][r] * 0.125f + ab;
                if (diag && j > qrow0 + r) v = -INFINITY;
                s[nf][r] = v;
            }
        }

        // online softmax: row max (16-lane shuffle), alpha, p, row sum
        float mnew[4], alpha[4];
        for (int r = 0; r < 4; ++r) {
            float mx = fmaxf(fmaxf(s[0][r], s[1][r]), fmaxf(s[2][r], s[3][r]));
            for (int off = 1; off < 16; off <<= 1) mx = fmaxf(mx, __shfl_xor(mx, off, 64));
            mnew[r] = fmaxf(m_prev[r], mx);
            alpha[r] = exp2f((m_prev[r] - mnew[r]) * 1.44269504f);
            m_prev[r] = mnew[r];
        }
        float rs[4] = {0.f, 0.f, 0.f, 0.f};
        for (int nf = 0; nf < 4; ++nf)
            for (int r = 0; r < 4; ++r) {
                float p = exp2f((s[nf][r] - mnew[r]) * 1.44269504f);
                rs[r] += p;
                Ps[(wave * 16 + quad * 4 + r) * LDT + nf * 16 + l16] = (bf16)p;
            }
        for (int r = 0; r < 4; ++r) {
            float t = rs[r];
            for (int off = 1; off < 16; off <<= 1) t += __shfl_xor(t, off, 64);
            l_sum[r] = l_sum[r] * alpha[r] + t;
        }
        for (int df = 0; df < 4; ++df)
            for (int r = 0; r < 4; ++r) acc_o[df][r] *= alpha[r];

        // PV: P (A-layout via LDS round-trip) x V^T-staged (B-layout)
        bf16x8 pf0 = *(const bf16x8*)&Ps[(wave * 16 + l16) * LDT + quad * 8];
        bf16x8 pf1 = *(const bf16x8*)&Ps[(wave * 16 + l16) * LDT + 32 + quad * 8];
        for (int df = 0; df < 4; ++df) {
            bf16x8 vf0 = *(const bf16x8*)&Vt[(df * 16 + l16) * LDT + quad * 8];
            bf16x8 vf1 = *(const bf16x8*)&Vt[(df * 16 + l16) * LDT + 32 + quad * 8];
            acc_o[df] = __builtin_amdgcn_mfma_f32_16x16x32_bf16(pf0, vf0, acc_o[df], 0, 0, 0);
            acc_o[df] = __builtin_amdgcn_mfma_f32_16x16x32_bf16(pf1, vf1, acc_o[df], 0, 0, 0);
        }
    }

    // epilogue: O[b,t,h,d] = acc/l
    for (int df = 0; df < 4; ++df)
        for (int r = 0; r < 4; ++r) {
            int t = qt * 64 + wave * 16 + quad * 4 + r;
            float o = acc_o[df][r] / l_sum[r];
            O[(((size_t)b * T_ + t) * H_ + h) * HD + df * 16 + l16] = (bf16)o;
        }
}

// ---------------------------------------------------------------- launch
extern "C" void kernel_launch(void* const* d_in, const int* in_sizes, int n_in,
                              void* d_out, int out_size, void* d_ws, size_t ws_size,
                              hipStream_t stream) {
    const float* x  = (const float*)d_in[0];
    const float* Wq = (const float*)d_in[1];
    const float* Wk = (const float*)d_in[2];
    const float* Wv = (const float*)d_in[3];
    const float* Wo = (const float*)d_in[4];
    float* out = (float*)d_out;

    const size_t M = (size_t)B_ * T_;        // 4096
    const size_t XE = M * D_;                // 4 Mi elems
    const size_t WE = (size_t)D_ * D_;       // 1 Mi elems

    char* ws = (char*)d_ws;
    size_t off = 0;
    auto carve = [&](size_t bytes) {
        void* p = ws + off;
        off += (bytes + 255) & ~(size_t)255;
        return p;
    };
    bf16* xb  = (bf16*)carve(XE * 2);        // x bf16; reused as attn_out later
    bf16* Wt  = (bf16*)carve(3 * WE * 2);    // Wq,Wk,Wv transposed [N][K]
    bf16* Wto = (bf16*)carve(WE * 2);        // Wo transposed
    bf16* QKV = (bf16*)carve(3 * XE * 2);    // Q,K,V in [B,H,T,hd]
    bf16* attn = xb;  // safe: xb fully consumed by gemm_qkv before attn_kernel runs

    cast_f32_bf16<<<dim3(XE / (4 * 256)), dim3(256), 0, stream>>>(x, xb, (int)XE);
    dim3 tg(16, 16);
    transpose_cast<<<tg, 256, 0, stream>>>(Wq, Wt + 0 * WE);
    transpose_cast<<<tg, 256, 0, stream>>>(Wk, Wt + 1 * WE);
    transpose_cast<<<tg, 256, 0, stream>>>(Wv, Wt + 2 * WE);
    transpose_cast<<<tg, 256, 0, stream>>>(Wo, Wto);

    gemm_bf16<<<dim3(D_ / 128, M / 128, 3), 256, 0, stream>>>(xb, Wt, QKV,
                                                              (int)M, D_, D_, 0);
    attn_kernel<<<dim3(T_ / 64, B_ * H_), 256, 0, stream>>>(QKV, QKV + XE, QKV + 2 * XE, attn);
    gemm_bf16<<<dim3(D_ / 128, M / 128, 1), 256, 0, stream>>>(attn, Wto, out,
                                                              (int)M, D_, D_, 1);
}

// Round 2
// 299.157 us; speedup vs baseline: 1.1142x; 1.1142x over previous
//
#include <hip/hip_runtime.h>
#include <hip/hip_bf16.h>
#include <math.h>

#define B_ 2
#define T_ 2048
#define D_ 1024
#define H_ 16
#define HD 64

typedef __bf16 bf16;
typedef bf16 bf16x8 __attribute__((ext_vector_type(8)));
typedef float f32x4 __attribute__((ext_vector_type(4)));

// ---------------------------------------------------------------- cast x->bf16
__global__ __launch_bounds__(256) void cast_f32_bf16(const float* __restrict__ in,
                                                     bf16* __restrict__ out, int n) {
    int i = (blockIdx.x * 256 + threadIdx.x) * 4;
    if (i + 3 < n) {
        float4 v = *(const float4*)(in + i);
        bf16 tmp[4] = {(bf16)v.x, (bf16)v.y, (bf16)v.z, (bf16)v.w};
        *(uint2*)(out + i) = *(const uint2*)tmp;  // 8B store
    }
}

// ------------------------------------------- W[k][n] f32 -> Wt[n][k] bf16 (1024x1024)
__global__ __launch_bounds__(256) void transpose_cast(const float* __restrict__ W,
                                                      bf16* __restrict__ Wt) {
    __shared__ bf16 tile[64 * 72];
    const int k0 = blockIdx.y * 64, n0 = blockIdx.x * 64;
    const int tid = threadIdx.x;
    for (int it = 0; it < 4; ++it) {
        int idx = it * 256 + tid;
        int r = idx >> 4;                // k row
        int c4 = (idx & 15) << 2;        // n col
        float4 v = *(const float4*)(W + (size_t)(k0 + r) * D_ + n0 + c4);
        tile[(c4 + 0) * 72 + r] = (bf16)v.x;
        tile[(c4 + 1) * 72 + r] = (bf16)v.y;
        tile[(c4 + 2) * 72 + r] = (bf16)v.z;
        tile[(c4 + 3) * 72 + r] = (bf16)v.w;
    }
    __syncthreads();
    for (int it = 0; it < 2; ++it) {
        int idx = it * 256 + tid;
        int r = idx >> 3;                // n row
        int c8 = (idx & 7) << 3;         // k col
        bf16x8 v = *(const bf16x8*)&tile[r * 72 + c8];
        *(bf16x8*)(Wt + (size_t)(n0 + r) * D_ + k0 + c8) = v;
    }
}

// ---------------------------------------------------------------- MFMA GEMM
// C[M,N] = A[M,K] @ Bt[N,K]^T.  BM=BN=128, BK=32, 256 thr = 4 waves, each 64x64.
// mode 0: out bf16; z=0(Q),1(K) -> [B,H,T,hd]; z=2(V) -> [B,H,hd,T] (transposed!)
// mode 1: out fp32, plain row-major
#define LDA 40

__global__ __launch_bounds__(256) void gemm_bf16(const bf16* __restrict__ A,
                                                 const bf16* __restrict__ Bt,
                                                 void* __restrict__ Cout,
                                                 int M, int N, int K, int mode) {
    __shared__ bf16 As[128 * LDA];
    __shared__ bf16 Bs[128 * LDA];
    const int tid = threadIdx.x;
    const int wave = tid >> 6, lane = tid & 63;
    const int quad = lane >> 4, l16 = lane & 15;
    const int wr = wave >> 1, wc = wave & 1;
    const int m0 = blockIdx.y * 128, n0 = blockIdx.x * 128;
    const int z = blockIdx.z;
    const bf16* Az = A;
    const bf16* Bz = Bt + (size_t)z * N * K;

    f32x4 acc[4][4];
    for (int mi = 0; mi < 4; ++mi)
        for (int ni = 0; ni < 4; ++ni) acc[mi][ni] = (f32x4){0.f, 0.f, 0.f, 0.f};

    for (int kb = 0; kb < K; kb += 32) {
        for (int it = 0; it < 2; ++it) {
            int idx = it * 256 + tid;
            int r = idx >> 2, c8 = (idx & 3) << 3;
            *(bf16x8*)&As[r * LDA + c8] = *(const bf16x8*)(Az + (size_t)(m0 + r) * K + kb + c8);
            *(bf16x8*)&Bs[r * LDA + c8] = *(const bf16x8*)(Bz + (size_t)(n0 + r) * K + kb + c8);
        }
        __syncthreads();
        bf16x8 af[4], bfr[4];
        for (int mi = 0; mi < 4; ++mi)
            af[mi] = *(const bf16x8*)&As[(wr * 64 + mi * 16 + l16) * LDA + quad * 8];
        for (int ni = 0; ni < 4; ++ni)
            bfr[ni] = *(const bf16x8*)&Bs[(wc * 64 + ni * 16 + l16) * LDA + quad * 8];
        for (int mi = 0; mi < 4; ++mi)
            for (int ni = 0; ni < 4; ++ni)
                acc[mi][ni] = __builtin_amdgcn_mfma_f32_16x16x32_bf16(af[mi], bfr[ni],
                                                                      acc[mi][ni], 0, 0, 0);
        __syncthreads();
    }

    // C/D layout: col = lane&15, row = quad*4 + reg
    if (mode == 0) {
        bf16* Cb = (bf16*)Cout + (size_t)z * M * N;
        for (int mi = 0; mi < 4; ++mi)
            for (int ni = 0; ni < 4; ++ni)
                for (int r = 0; r < 4; ++r) {
                    int m = m0 + wr * 64 + mi * 16 + quad * 4 + r;
                    int n = n0 + wc * 64 + ni * 16 + l16;
                    int b = m >> 11, t = m & (T_ - 1);
                    int h = n >> 6, d = n & (HD - 1);
                    size_t idx = (z == 2)
                        ? ((((size_t)b * H_ + h) * HD + d) * T_ + t)        // V^T [B,H,hd,T]
                        : (((((size_t)b * H_ + h) * T_ + t) << 6) + d);     // [B,H,T,hd]
                    Cb[idx] = (bf16)acc[mi][ni][r];
                }
    } else {
        float* Cf = (float*)Cout;
        for (int mi = 0; mi < 4; ++mi)
            for (int ni = 0; ni < 4; ++ni)
                for (int r = 0; r < 4; ++r) {
                    int m = m0 + wr * 64 + mi * 16 + quad * 4 + r;
                    int n = n0 + wc * 64 + ni * 16 + l16;
                    Cf[(size_t)m * N + n] = acc[mi][ni][r];
                }
    }
}

// ---------------------------------------------------------------- flash attention
// Q,K: [B,H,T,hd] bf16.  Vt: [B,H,hd,T] bf16 (pre-transposed).  Out: [B,T,H,hd] bf16.
// Block = 256 thr = 4 waves; Br=64 (16 q-rows/wave), Bc=128.
#define LDK 72    // Ks pitch (36 dw, ==4 mod 8 -> bank spread)
#define LDP 136   // Ps/Vs pitch (68 dw, ==4 mod 8; 272B rows, 16B aligned)

__global__ __launch_bounds__(256) void attn_kernel(const bf16* __restrict__ Q,
                                                   const bf16* __restrict__ K,
                                                   const bf16* __restrict__ Vt,
                                                   bf16* __restrict__ O) {
    __shared__ bf16 Ks[128 * LDK];  // [key][dim]
    __shared__ bf16 Vs[64 * LDP];   // [dim][key]
    __shared__ bf16 Ps[64 * LDP];   // [q_local][key]

    const int bx = blockIdx.x, by = blockIdx.y;
    const int qt = 31 - ((bx + by) & 31);      // diagonal shuffle for load balance
    const int bh = by;
    const int h = bh & (H_ - 1), b = bh >> 4;
    const int tid = threadIdx.x;
    const int wave = tid >> 6, lane = tid & 63;
    const int quad = lane >> 4, l16 = lane & 15;

    const bf16* Qb = Q + (size_t)bh * T_ * HD;
    const bf16* Kb = K + (size_t)bh * T_ * HD;
    const bf16* Vb = Vt + (size_t)bh * HD * T_;   // [hd][T]

    const float LOG2E = 1.44269504f;
    const float slope2 = exp2f(-0.5f * (float)(h + 1)) * LOG2E;  // log2-domain slope
    const float c1 = 0.125f * LOG2E;                             // 1/sqrt(64) * log2e

    // Q fragments (A layout: m=l16, k=quad*8+j), two 32-wide k-steps over hd=64
    bf16x8 qf[2];
    {
        const bf16* qrow = Qb + (size_t)(qt * 64 + wave * 16 + l16) * HD + quad * 8;
        qf[0] = *(const bf16x8*)(qrow);
        qf[1] = *(const bf16x8*)(qrow + 32);
    }

    f32x4 acc_o[4];
    float m_prev[4], l_sum[4];
    for (int df = 0; df < 4; ++df) acc_o[df] = (f32x4){0.f, 0.f, 0.f, 0.f};
    for (int r = 0; r < 4; ++r) { m_prev[r] = -INFINITY; l_sum[r] = 0.f; }

    const int qrow0 = qt * 64 + wave * 16 + quad * 4;  // + r
    const int nkt = (qt >> 1) + 1;                     // number of 128-key tiles

    for (int kt = 0; kt < nkt; ++kt) {
        const bool last = (kt == nkt - 1);
        __syncthreads();
        for (int it = 0; it < 4; ++it) {
            int idx = it * 256 + tid;
            // Ks: 128 key-rows x 8 groups of 8 dims
            int rk = idx >> 3, ck = (idx & 7) << 3;
            *(bf16x8*)&Ks[rk * LDK + ck] =
                *(const bf16x8*)(Kb + (size_t)(kt * 128 + rk) * HD + ck);
            // Vs: 64 dim-rows x 16 groups of 8 keys (direct, V pre-transposed)
            int rv = idx >> 4, cv = (idx & 15) << 3;
            *(bf16x8*)&Vs[rv * LDP + cv] =
                *(const bf16x8*)(Vb + (size_t)rv * T_ + kt * 128 + cv);
        }
        __syncthreads();

        // S = Q K^T  (8 key-frags x 2 k-steps), directly in log2 domain
        f32x4 s[8];
        for (int nf = 0; nf < 8; ++nf) {
            bf16x8 kf0 = *(const bf16x8*)&Ks[(nf * 16 + l16) * LDK + quad * 8];
            bf16x8 kf1 = *(const bf16x8*)&Ks[(nf * 16 + l16) * LDK + 32 + quad * 8];
            f32x4 z = (f32x4){0.f, 0.f, 0.f, 0.f};
            z = __builtin_amdgcn_mfma_f32_16x16x32_bf16(qf[0], kf0, z, 0, 0, 0);
            z = __builtin_amdgcn_mfma_f32_16x16x32_bf16(qf[1], kf1, z, 0, 0, 0);
            s[nf] = z;
        }
        for (int nf = 0; nf < 8; ++nf) {
            int j = kt * 128 + nf * 16 + l16;
            float ab = slope2 * (float)(j - (T_ - 1));
            for (int r = 0; r < 4; ++r) {
                float v = s[nf][r] * c1 + ab;
                if (last && j > qrow0 + r) v = -INFINITY;
                s[nf][r] = v;
            }
        }

        // online softmax (log2 domain)
        float mnew[4], alpha[4];
        for (int r = 0; r < 4; ++r) {
            float mx = fmaxf(fmaxf(fmaxf(s[0][r], s[1][r]), fmaxf(s[2][r], s[3][r])),
                             fmaxf(fmaxf(s[4][r], s[5][r]), fmaxf(s[6][r], s[7][r])));
            for (int off = 1; off < 16; off <<= 1) mx = fmaxf(mx, __shfl_xor(mx, off, 64));
            mnew[r] = fmaxf(m_prev[r], mx);
            alpha[r] = exp2f(m_prev[r] - mnew[r]);
            m_prev[r] = mnew[r];
        }
        float rs[4] = {0.f, 0.f, 0.f, 0.f};
        for (int nf = 0; nf < 8; ++nf)
            for (int r = 0; r < 4; ++r) {
                float p = exp2f(s[nf][r] - mnew[r]);
                rs[r] += p;
                Ps[(wave * 16 + quad * 4 + r) * LDP + nf * 16 + l16] = (bf16)p;
            }
        for (int r = 0; r < 4; ++r) {
            float t = rs[r];
            for (int off = 1; off < 16; off <<= 1) t += __shfl_xor(t, off, 64);
            l_sum[r] = l_sum[r] * alpha[r] + t;
        }
        for (int df = 0; df < 4; ++df)
            for (int r = 0; r < 4; ++r) acc_o[df][r] *= alpha[r];

        // PV: P (A-frag, own wave's rows -> no barrier needed) x V (B-frag)
        bf16x8 pf[4];
        for (int g = 0; g < 4; ++g)
            pf[g] = *(const bf16x8*)&Ps[(wave * 16 + l16) * LDP + g * 32 + quad * 8];
        for (int df = 0; df < 4; ++df)
            for (int g = 0; g < 4; ++g) {
                bf16x8 vf = *(const bf16x8*)&Vs[(df * 16 + l16) * LDP + g * 32 + quad * 8];
                acc_o[df] = __builtin_amdgcn_mfma_f32_16x16x32_bf16(pf[g], vf, acc_o[df], 0, 0, 0);
            }
    }

    // epilogue: O[b,t,h,d] = acc/l
    for (int df = 0; df < 4; ++df)
        for (int r = 0; r < 4; ++r) {
            int t = qt * 64 + wave * 16 + quad * 4 + r;
            float o = acc_o[df][r] / l_sum[r];
            O[(((size_t)b * T_ + t) * H_ + h) * HD + df * 16 + l16] = (bf16)o;
        }
}

// ---------------------------------------------------------------- launch
extern "C" void kernel_launch(void* const* d_in, const int* in_sizes, int n_in,
                              void* d_out, int out_size, void* d_ws, size_t ws_size,
                              hipStream_t stream) {
    const float* x  = (const float*)d_in[0];
    const float* Wq = (const float*)d_in[1];
    const float* Wk = (const float*)d_in[2];
    const float* Wv = (const float*)d_in[3];
    const float* Wo = (const float*)d_in[4];
    float* out = (float*)d_out;

    const size_t M = (size_t)B_ * T_;        // 4096
    const size_t XE = M * D_;                // 4 Mi elems
    const size_t WE = (size_t)D_ * D_;       // 1 Mi elems

    char* ws = (char*)d_ws;
    size_t off = 0;
    auto carve = [&](size_t bytes) {
        void* p = ws + off;
        off += (bytes + 255) & ~(size_t)255;
        return p;
    };
    bf16* xb  = (bf16*)carve(XE * 2);        // x bf16; reused as attn_out later
    bf16* Wt  = (bf16*)carve(3 * WE * 2);    // Wq,Wk,Wv transposed [N][K]
    bf16* Wto = (bf16*)carve(WE * 2);        // Wo transposed
    bf16* QKV = (bf16*)carve(3 * XE * 2);    // Q,K [B,H,T,hd]; V [B,H,hd,T]
    bf16* attn = xb;  // safe: xb fully consumed by QKV gemm before attn_kernel runs

    cast_f32_bf16<<<dim3(XE / (4 * 256)), dim3(256), 0, stream>>>(x, xb, (int)XE);
    dim3 tg(16, 16);
    transpose_cast<<<tg, 256, 0, stream>>>(Wq, Wt + 0 * WE);
    transpose_cast<<<tg, 256, 0, stream>>>(Wk, Wt + 1 * WE);
    transpose_cast<<<tg, 256, 0, stream>>>(Wv, Wt + 2 * WE);
    transpose_cast<<<tg, 256, 0, stream>>>(Wo, Wto);

    gemm_bf16<<<dim3(D_ / 128, M / 128, 3), 256, 0, stream>>>(xb, Wt, QKV,
                                                              (int)M, D_, D_, 0);
    attn_kernel<<<dim3(32, B_ * H_), 256, 0, stream>>>(QKV, QKV + XE, QKV + 2 * XE, attn);
    gemm_bf16<<<dim3(D_ / 128, M / 128, 1), 256, 0, stream>>>(attn, Wto, out,
                                                              (int)M, D_, D_, 1);
}

// Round 4
// 249.651 us; speedup vs baseline: 1.3352x; 1.1983x over previous
//
#include <hip/hip_runtime.h>
#include <hip/hip_bf16.h>
#include <math.h>

#define B_ 2
#define T_ 2048
#define D_ 1024
#define H_ 16
#define HD 64

typedef __bf16 bf16;
typedef bf16 bf16x8 __attribute__((ext_vector_type(8)));
typedef bf16 bf16x4 __attribute__((ext_vector_type(4)));
typedef short short4v __attribute__((ext_vector_type(4)));
typedef float f32x4 __attribute__((ext_vector_type(4)));

// 16x16x16 bf16 MFMA (K=16). Builtin is the gfx90a-era name; instruction exists on
// gfx950 (ISA §10: v_mfma_f32_16x16x16_bf16, A/B = 2 VGPRs each, C/D = 4).
// Host pass must never see an amdgcn builtin name it doesn't know -> device guard.
static __device__ __forceinline__ f32x4 mfma16x16x16(bf16x4 a, bf16x4 b, f32x4 c) {
#if defined(__HIP_DEVICE_COMPILE__)
# if __has_builtin(__builtin_amdgcn_mfma_f32_16x16x16bf16_1k)
    return __builtin_amdgcn_mfma_f32_16x16x16bf16_1k(
        __builtin_bit_cast(short4v, a), __builtin_bit_cast(short4v, b), c, 0, 0, 0);
# else
    asm("v_mfma_f32_16x16x16_bf16 %0, %1, %2, %0" : "+v"(c) : "v"(a), "v"(b));
    return c;
# endif
#else
    (void)a; (void)b;
    return c;  // host stub, never executed
#endif
}

// ---------------------------------------------------------------- cast x->bf16
__global__ __launch_bounds__(256) void cast_f32_bf16(const float* __restrict__ in,
                                                     bf16* __restrict__ out, int n) {
    int i = (blockIdx.x * 256 + threadIdx.x) * 4;
    if (i + 3 < n) {
        float4 v = *(const float4*)(in + i);
        bf16 tmp[4] = {(bf16)v.x, (bf16)v.y, (bf16)v.z, (bf16)v.w};
        *(uint2*)(out + i) = *(const uint2*)tmp;  // 8B store
    }
}

// ------------------------------------------- W[k][n] f32 -> Wt[n][k] bf16 (1024x1024)
__global__ __launch_bounds__(256) void transpose_cast(const float* __restrict__ W,
                                                      bf16* __restrict__ Wt) {
    __shared__ bf16 tile[64 * 72];
    const int k0 = blockIdx.y * 64, n0 = blockIdx.x * 64;
    const int tid = threadIdx.x;
    for (int it = 0; it < 4; ++it) {
        int idx = it * 256 + tid;
        int r = idx >> 4;                // k row
        int c4 = (idx & 15) << 2;        // n col
        float4 v = *(const float4*)(W + (size_t)(k0 + r) * D_ + n0 + c4);
        tile[(c4 + 0) * 72 + r] = (bf16)v.x;
        tile[(c4 + 1) * 72 + r] = (bf16)v.y;
        tile[(c4 + 2) * 72 + r] = (bf16)v.z;
        tile[(c4 + 3) * 72 + r] = (bf16)v.w;
    }
    __syncthreads();
    for (int it = 0; it < 2; ++it) {
        int idx = it * 256 + tid;
        int r = idx >> 3;                // n row
        int c8 = (idx & 7) << 3;         // k col
        bf16x8 v = *(const bf16x8*)&tile[r * 72 + c8];
        *(bf16x8*)(Wt + (size_t)(n0 + r) * D_ + k0 + c8) = v;
    }
}

// ---------------------------------------------------------------- MFMA GEMM
// C[M,N] = A[M,K] @ Bt[N,K]^T.  BM=BN=128, BK=32, 256 thr = 4 waves, each 64x64.
// mode 0: out bf16; z=0(Q),1(K) -> [B,H,T,hd]; z=2(V) -> [B,H,hd,T] (transposed!)
// mode 1: out fp32, plain row-major
#define LDA 40

__global__ __launch_bounds__(256) void gemm_bf16(const bf16* __restrict__ A,
                                                 const bf16* __restrict__ Bt,
                                                 void* __restrict__ Cout,
                                                 int M, int N, int K, int mode) {
    __shared__ bf16 As[128 * LDA];
    __shared__ bf16 Bs[128 * LDA];
    const int tid = threadIdx.x;
    const int wave = tid >> 6, lane = tid & 63;
    const int quad = lane >> 4, l16 = lane & 15;
    const int wr = wave >> 1, wc = wave & 1;
    const int m0 = blockIdx.y * 128, n0 = blockIdx.x * 128;
    const int z = blockIdx.z;
    const bf16* Az = A;
    const bf16* Bz = Bt + (size_t)z * N * K;

    f32x4 acc[4][4];
    for (int mi = 0; mi < 4; ++mi)
        for (int ni = 0; ni < 4; ++ni) acc[mi][ni] = (f32x4){0.f, 0.f, 0.f, 0.f};

    for (int kb = 0; kb < K; kb += 32) {
        for (int it = 0; it < 2; ++it) {
            int idx = it * 256 + tid;
            int r = idx >> 2, c8 = (idx & 3) << 3;
            *(bf16x8*)&As[r * LDA + c8] = *(const bf16x8*)(Az + (size_t)(m0 + r) * K + kb + c8);
            *(bf16x8*)&Bs[r * LDA + c8] = *(const bf16x8*)(Bz + (size_t)(n0 + r) * K + kb + c8);
        }
        __syncthreads();
        bf16x8 af[4], bfr[4];
        for (int mi = 0; mi < 4; ++mi)
            af[mi] = *(const bf16x8*)&As[(wr * 64 + mi * 16 + l16) * LDA + quad * 8];
        for (int ni = 0; ni < 4; ++ni)
            bfr[ni] = *(const bf16x8*)&Bs[(wc * 64 + ni * 16 + l16) * LDA + quad * 8];
        for (int mi = 0; mi < 4; ++mi)
            for (int ni = 0; ni < 4; ++ni)
                acc[mi][ni] = __builtin_amdgcn_mfma_f32_16x16x32_bf16(af[mi], bfr[ni],
                                                                      acc[mi][ni], 0, 0, 0);
        __syncthreads();
    }

    // C/D layout: col = lane&15, row = quad*4 + reg
    if (mode == 0) {
        bf16* Cb = (bf16*)Cout + (size_t)z * M * N;
        for (int mi = 0; mi < 4; ++mi)
            for (int ni = 0; ni < 4; ++ni)
                for (int r = 0; r < 4; ++r) {
                    int m = m0 + wr * 64 + mi * 16 + quad * 4 + r;
                    int n = n0 + wc * 64 + ni * 16 + l16;
                    int b = m >> 11, t = m & (T_ - 1);
                    int h = n >> 6, d = n & (HD - 1);
                    size_t idx = (z == 2)
                        ? ((((size_t)b * H_ + h) * HD + d) * T_ + t)        // V^T [B,H,hd,T]
                        : (((((size_t)b * H_ + h) * T_ + t) << 6) + d);     // [B,H,T,hd]
                    Cb[idx] = (bf16)acc[mi][ni][r];
                }
    } else {
        float* Cf = (float*)Cout;
        for (int mi = 0; mi < 4; ++mi)
            for (int ni = 0; ni < 4; ++ni)
                for (int r = 0; r < 4; ++r) {
                    int m = m0 + wr * 64 + mi * 16 + quad * 4 + r;
                    int n = n0 + wc * 64 + ni * 16 + l16;
                    Cf[(size_t)m * N + n] = acc[mi][ni][r];
                }
    }
}

// ---------------------------------------------------------------- flash attention (S^T form)
// Q,K: [B,H,T,hd] bf16.  Vt: [B,H,hd,T] bf16 (pre-transposed).  Out: [B,T,H,hd] bf16.
// Block = 256 thr = 4 waves; each wave owns 16 queries (l16), Bc=128.
// S^T = K*Q^T via mfma(A=K,B=Q): C-layout key=quad*4+r, query=l16 -- which IS the
// B-operand layout of 16x16x16 MFMA (k=quad*4+j) -> P feeds PV straight from registers.
// O^T accumulates in C-layout: d=quad*4+r, query=l16.
#define LDK 72    // Ks pitch
#define LDP 136   // Vs pitch

__global__ __launch_bounds__(256, 4) void attn_kernel(const bf16* __restrict__ Q,
                                                      const bf16* __restrict__ K,
                                                      const bf16* __restrict__ Vt,
                                                      bf16* __restrict__ O) {
    __shared__ bf16 Ks[128 * LDK];  // [key][dim]
    __shared__ bf16 Vs[64 * LDP];   // [dim][key]

    const int bx = blockIdx.x, by = blockIdx.y;
    const int qt = 31 - ((bx + by) & 31);      // diagonal shuffle for load balance
    const int bh = by;
    const int h = bh & (H_ - 1), b = bh >> 4;
    const int tid = threadIdx.x;
    const int wave = tid >> 6, lane = tid & 63;
    const int quad = lane >> 4, l16 = lane & 15;

    const bf16* Qb = Q + (size_t)bh * T_ * HD;
    const bf16* Kb = K + (size_t)bh * T_ * HD;
    const bf16* Vb = Vt + (size_t)bh * HD * T_;   // [hd][T]

    const float LOG2E = 1.44269504f;
    const float slope2 = exp2f(-0.5f * (float)(h + 1)) * LOG2E;  // log2-domain slope
    const float c1 = 0.125f * LOG2E;                             // 1/sqrt(64) * log2e

    // Q fragment, B-operand layout of 16x16x32 (n=l16, k=quad*8+j), two 32-wide k-steps
    bf16x8 qf[2];
    {
        const bf16* qrow = Qb + (size_t)(qt * 64 + wave * 16 + l16) * HD + quad * 8;
        qf[0] = *(const bf16x8*)(qrow);
        qf[1] = *(const bf16x8*)(qrow + 32);
    }

    f32x4 acc[4];                    // O^T: d = df*16+quad*4+r, query = l16
    for (int df = 0; df < 4; ++df) acc[df] = (f32x4){0.f, 0.f, 0.f, 0.f};
    float m_run = -INFINITY, l_run = 0.f;

    const int qglob = qt * 64 + wave * 16 + l16;   // this lane's query row
    const int nkt = (qt >> 1) + 1;                 // number of 128-key tiles

    for (int kt = 0; kt < nkt; ++kt) {
        const bool last = (kt == nkt - 1);
        __syncthreads();
        for (int it = 0; it < 4; ++it) {
            int idx = it * 256 + tid;
            int rk = idx >> 3, ck = (idx & 7) << 3;
            *(bf16x8*)&Ks[rk * LDK + ck] =
                *(const bf16x8*)(Kb + (size_t)(kt * 128 + rk) * HD + ck);
            int rv = idx >> 4, cv = (idx & 15) << 3;
            *(bf16x8*)&Vs[rv * LDP + cv] =
                *(const bf16x8*)(Vb + (size_t)rv * T_ + kt * 128 + cv);
        }
        __syncthreads();

        // S^T = K Q^T: 8 key-blocks x 2 k-steps.  s[nf][r]: key=nf*16+quad*4+r, query=l16
        f32x4 s[8];
        for (int nf = 0; nf < 8; ++nf) {
            bf16x8 kf0 = *(const bf16x8*)&Ks[(nf * 16 + l16) * LDK + quad * 8];
            bf16x8 kf1 = *(const bf16x8*)&Ks[(nf * 16 + l16) * LDK + 32 + quad * 8];
            f32x4 z = (f32x4){0.f, 0.f, 0.f, 0.f};
            z = __builtin_amdgcn_mfma_f32_16x16x32_bf16(kf0, qf[0], z, 0, 0, 0);
            z = __builtin_amdgcn_mfma_f32_16x16x32_bf16(kf1, qf[1], z, 0, 0, 0);
            s[nf] = z;
        }

        // scale + alibi (log2 domain); causal mask only on the last tile
        const int jbase = kt * 128 + quad * 4;
        for (int nf = 0; nf < 8; ++nf)
            for (int r = 0; r < 4; ++r) {
                int j = jbase + nf * 16 + r;
                s[nf][r] = s[nf][r] * c1 + slope2 * (float)(j - (T_ - 1));
            }
        if (last) {
            for (int nf = 0; nf < 8; ++nf)
                for (int r = 0; r < 4; ++r)
                    if (jbase + nf * 16 + r > qglob) s[nf][r] = -INFINITY;
        }

        // online softmax, per-lane scalar state (query = l16); reduce across quads only
        float mx = -INFINITY;
        for (int nf = 0; nf < 8; ++nf) {
            float a = fmaxf(fmaxf(s[nf][0], s[nf][1]), fmaxf(s[nf][2], s[nf][3]));
            mx = fmaxf(mx, a);
        }
        mx = fmaxf(mx, __shfl_xor(mx, 16, 64));
        mx = fmaxf(mx, __shfl_xor(mx, 32, 64));
        const float mnew = fmaxf(m_run, mx);
        const float alpha = exp2f(m_run - mnew);
        m_run = mnew;

        float rs = 0.f;
        bf16x4 pf[8];                 // B-operand of 16x16x16: key=quad*4+j, query=l16
        for (int nf = 0; nf < 8; ++nf) {
            float p0 = exp2f(s[nf][0] - mnew);
            float p1 = exp2f(s[nf][1] - mnew);
            float p2 = exp2f(s[nf][2] - mnew);
            float p3 = exp2f(s[nf][3] - mnew);
            rs += (p0 + p1) + (p2 + p3);
            pf[nf] = (bf16x4){(bf16)p0, (bf16)p1, (bf16)p2, (bf16)p3};
        }
        rs += __shfl_xor(rs, 16, 64);
        rs += __shfl_xor(rs, 32, 64);
        l_run = l_run * alpha + rs;
        for (int df = 0; df < 4; ++df) acc[df] *= alpha;

        // O^T += V^T P^T: A = V^T frag (m=d=l16, k=key=quad*4+j), B = pf (registers!)
        for (int nf = 0; nf < 8; ++nf)
            for (int df = 0; df < 4; ++df) {
                bf16x4 vf = *(const bf16x4*)&Vs[(df * 16 + l16) * LDP + nf * 16 + quad * 4];
                acc[df] = mfma16x16x16(vf, pf[nf], acc[df]);
            }
    }

    // epilogue: O[b,t,h,d], d = df*16+quad*4+r (4 consecutive -> 8B store)
    const float inv = 1.0f / l_run;
    const int t = qglob;
    for (int df = 0; df < 4; ++df) {
        bf16 o4[4];
        for (int r = 0; r < 4; ++r) o4[r] = (bf16)(acc[df][r] * inv);
        *(uint2*)&O[(((size_t)b * T_ + t) * H_ + h) * HD + df * 16 + quad * 4] =
            *(const uint2*)o4;
    }
}

// ---------------------------------------------------------------- launch
extern "C" void kernel_launch(void* const* d_in, const int* in_sizes, int n_in,
                              void* d_out, int out_size, void* d_ws, size_t ws_size,
                              hipStream_t stream) {
    const float* x  = (const float*)d_in[0];
    const float* Wq = (const float*)d_in[1];
    const float* Wk = (const float*)d_in[2];
    const float* Wv = (const float*)d_in[3];
    const float* Wo = (const float*)d_in[4];
    float* out = (float*)d_out;

    const size_t M = (size_t)B_ * T_;        // 4096
    const size_t XE = M * D_;                // 4 Mi elems
    const size_t WE = (size_t)D_ * D_;       // 1 Mi elems

    char* ws = (char*)d_ws;
    size_t off = 0;
    auto carve = [&](size_t bytes) {
        void* p = ws + off;
        off += (bytes + 255) & ~(size_t)255;
        return p;
    };
    bf16* xb  = (bf16*)carve(XE * 2);        // x bf16; reused as attn_out later
    bf16* Wt  = (bf16*)carve(3 * WE * 2);    // Wq,Wk,Wv transposed [N][K]
    bf16* Wto = (bf16*)carve(WE * 2);        // Wo transposed
    bf16* QKV = (bf16*)carve(3 * XE * 2);    // Q,K [B,H,T,hd]; V [B,H,hd,T]
    bf16* attn = xb;  // safe: xb fully consumed by QKV gemm before attn_kernel runs

    cast_f32_bf16<<<dim3(XE / (4 * 256)), dim3(256), 0, stream>>>(x, xb, (int)XE);
    dim3 tg(16, 16);
    transpose_cast<<<tg, 256, 0, stream>>>(Wq, Wt + 0 * WE);
    transpose_cast<<<tg, 256, 0, stream>>>(Wk, Wt + 1 * WE);
    transpose_cast<<<tg, 256, 0, stream>>>(Wv, Wt + 2 * WE);
    transpose_cast<<<tg, 256, 0, stream>>>(Wo, Wto);

    gemm_bf16<<<dim3(D_ / 128, M / 128, 3), 256, 0, stream>>>(xb, Wt, QKV,
                                                              (int)M, D_, D_, 0);
    attn_kernel<<<dim3(32, B_ * H_), 256, 0, stream>>>(QKV, QKV + XE, QKV + 2 * XE, attn);
    gemm_bf16<<<dim3(D_ / 128, M / 128, 1), 256, 0, stream>>>(attn, Wto, out,
                                                              (int)M, D_, D_, 1);
}